// Round 2
// baseline (1391.967 us; speedup 1.0000x reference)
//
#include <hip/hip_runtime.h>

#define N_NODES 100000
#define N_EDGES 1600000
#define NB_SCAN 49  // ceil(100000/2048)

// ---------------- CSR build ----------------

__global__ void k_zero(int* __restrict__ p, int n) {
    int i = blockIdx.x * blockDim.x + threadIdx.x;
    if (i < n) p[i] = 0;
}

__global__ void k_count(const int* __restrict__ dst, int* __restrict__ cnt) {
    int e = blockIdx.x * blockDim.x + threadIdx.x;
    if (e < N_EDGES) atomicAdd(&cnt[dst[e]], 1);
}

// per-block (2048 elems) sums
__global__ void k_partial(const int* __restrict__ cnt, int* __restrict__ part) {
    __shared__ int red[256];
    int t = threadIdx.x;
    int base = blockIdx.x * 2048 + t * 8;
    int s = 0;
    if (base < N_NODES) {  // N_NODES % 8 == 0
        const int4* p = (const int4*)(cnt + base);
        int4 a = p[0], b = p[1];
        s = a.x + a.y + a.z + a.w + b.x + b.y + b.z + b.w;
    }
    red[t] = s;
    __syncthreads();
    for (int d = 128; d > 0; d >>= 1) {
        if (t < d) red[t] += red[t + d];
        __syncthreads();
    }
    if (t == 0) part[blockIdx.x] = red[0];
}

__global__ void k_scan_part(int* __restrict__ part, int nb) {
    int lane = threadIdx.x;
    int v = (lane < nb) ? part[lane] : 0;
    int incl = v;
    #pragma unroll
    for (int d = 1; d < 64; d <<= 1) {
        int u = __shfl_up(incl, d, 64);
        if (lane >= d) incl += u;
    }
    if (lane < nb) part[lane] = incl - v;
}

__global__ void k_scan_chunks(const int* __restrict__ cnt, const int* __restrict__ part,
                              int* __restrict__ off) {
    __shared__ int wtot[4];
    __shared__ int wexc[4];
    int t = threadIdx.x, b = blockIdx.x;
    int base = b * 2048 + t * 8;
    int4 a = {0, 0, 0, 0}, c = {0, 0, 0, 0};
    if (base < N_NODES) {
        const int4* p = (const int4*)(cnt + base);
        a = p[0];
        c = p[1];
    }
    int s0 = a.x, s1 = s0 + a.y, s2 = s1 + a.z, s3 = s2 + a.w;
    int s4 = s3 + c.x, s5 = s4 + c.y, s6 = s5 + c.z, s7 = s6 + c.w;
    int tot = s7;
    int lane = t & 63, wid = t >> 6;
    int incl = tot;
    #pragma unroll
    for (int d = 1; d < 64; d <<= 1) {
        int u = __shfl_up(incl, d, 64);
        if (lane >= d) incl += u;
    }
    if (lane == 63) wtot[wid] = incl;
    __syncthreads();
    if (t == 0) {
        int r = 0;
        for (int i = 0; i < 4; i++) { int v = wtot[i]; wexc[i] = r; r += v; }
    }
    __syncthreads();
    int texc = incl - tot + wexc[wid] + part[b];
    if (base < N_NODES) {
        int4 o0 = {texc, texc + s0, texc + s1, texc + s2};
        int4 o1 = {texc + s3, texc + s4, texc + s5, texc + s6};
        ((int4*)(off + base))[0] = o0;
        ((int4*)(off + base))[1] = o1;
    }
}

// scatter edge into CSR position; pack edge id (21b) + local-dst (6b) into 32b
__global__ void k_scatter(const int* __restrict__ dst, const int* __restrict__ off,
                          int* __restrict__ cur, unsigned* __restrict__ code32) {
    int e = blockIdx.x * blockDim.x + threadIdx.x;
    if (e < N_EDGES) {
        int d = dst[e];
        int p = off[d] + atomicAdd(&cur[d], 1);
        code32[p] = ((unsigned)e << 6) | (unsigned)(d & 63);
    }
}

// ---------------- fused aggregate + 2 GEMMs + epilogue ----------------
// block = 256 threads, 64 nodes. Phase 1 is EDGE-parallel: the block's 64
// nodes own a contiguous CSR range [off[base], off[base+64]); 16 lane-groups
// each take one edge per iteration (strided), lane loads a float4 (16B slice)
// of nf[src] and ef[e], accumulated into LDS agg via ds_add_f32 atomics.
// All iterations independent -> deep load pipelining (latency fix vs r1).
__global__ __launch_bounds__(256) void k_node(
    const float* __restrict__ nf, const float* __restrict__ ef,
    const int* __restrict__ src, const int* __restrict__ cnt,
    const int* __restrict__ off, const unsigned* __restrict__ code32,
    const float* __restrict__ Wm, const float* __restrict__ bm,
    const float* __restrict__ Wa, const float* __restrict__ ba,
    float* __restrict__ out) {
    __shared__ __align__(16) float agg[64][132];  // stride 132: 16B-aligned rows, spreads banks
    __shared__ __align__(16) float hn[64][68];
    __shared__ float degl[64];

    int tid = threadIdx.x;
    int base = blockIdx.x * 64;

    // zero agg, load degrees
    {
        float* af = &agg[0][0];
        for (int i = tid; i < 64 * 132; i += 256) af[i] = 0.f;
        if (tid < 64) degl[tid] = (base + tid < N_NODES) ? (float)cnt[base + tid] : 0.f;
    }
    __syncthreads();

    // ---- phase 1: edge-parallel aggregation ----
    {
        int s0 = off[base];
        int s1 = (base + 64 < N_NODES) ? off[base + 64] : N_EDGES;
        int g = tid >> 4;           // group 0..15, one edge per group-iteration
        int l4 = (tid & 15) << 2;   // dim base: 16 lanes x float4 = 64 dims
        for (int p = s0 + g; p < s1; p += 16) {
            unsigned c = code32[p];
            int e = (int)(c >> 6);
            int dv = (int)(c & 63u);
            int sv = src[e];
            float4 a = *(const float4*)(nf + (size_t)sv * 64 + l4);
            float4 b = *(const float4*)(ef + (size_t)e * 64 + l4);
            atomicAdd(&agg[dv][l4 + 0], a.x);
            atomicAdd(&agg[dv][l4 + 1], a.y);
            atomicAdd(&agg[dv][l4 + 2], a.z);
            atomicAdd(&agg[dv][l4 + 3], a.w);
            atomicAdd(&agg[dv][64 + l4 + 0], b.x);
            atomicAdd(&agg[dv][64 + l4 + 1], b.y);
            atomicAdd(&agg[dv][64 + l4 + 2], b.z);
            atomicAdd(&agg[dv][64 + l4 + 3], b.w);
        }
    }
    __syncthreads();

    // ---- GEMM1: hn = (Wm @ agg)/deg + bm ----
    int og = (tid & 15) * 4;   // output dim group
    int ng = (tid >> 4) * 4;   // node group
    float acc[4][4] = {};
    const float4* Wm4 = (const float4*)Wm;  // row o = 32 float4
    #pragma unroll 4
    for (int k4 = 0; k4 < 32; k4++) {
        float4 av[4], wv[4];
        #pragma unroll
        for (int i = 0; i < 4; i++) av[i] = *(const float4*)&agg[ng + i][k4 * 4];
        #pragma unroll
        for (int j = 0; j < 4; j++) wv[j] = Wm4[(og + j) * 32 + k4];
        #pragma unroll
        for (int i = 0; i < 4; i++)
            #pragma unroll
            for (int j = 0; j < 4; j++)
                acc[i][j] += av[i].x * wv[j].x + av[i].y * wv[j].y +
                             av[i].z * wv[j].z + av[i].w * wv[j].w;
    }
    #pragma unroll
    for (int i = 0; i < 4; i++) {
        float d = degl[ng + i];
        float inv = (d > 0.f) ? 1.f / d : 0.f;
        #pragma unroll
        for (int j = 0; j < 4; j++) {
            float v = (d > 0.f) ? acc[i][j] * inv + bm[og + j] : 0.f;
            hn[ng + i][og + j] = v;
        }
    }
    __syncthreads();

    // ---- GEMM2: out = relu(h @ WaH^T + hn @ WaN^T + ba) ----
    float acc2[4][4] = {};
    const float4* Wa4 = (const float4*)Wa;  // row o = 32 float4; k<64 -> first 16
    #pragma unroll 4
    for (int k4 = 0; k4 < 16; k4++) {
        float4 hv[4], wv[4];
        #pragma unroll
        for (int i = 0; i < 4; i++) {
            int n = base + ng + i;
            if (n < N_NODES)
                hv[i] = ((const float4*)(nf + (size_t)n * 64))[k4];
            else
                hv[i] = make_float4(0.f, 0.f, 0.f, 0.f);
        }
        #pragma unroll
        for (int j = 0; j < 4; j++) wv[j] = Wa4[(og + j) * 32 + k4];
        #pragma unroll
        for (int i = 0; i < 4; i++)
            #pragma unroll
            for (int j = 0; j < 4; j++)
                acc2[i][j] += hv[i].x * wv[j].x + hv[i].y * wv[j].y +
                              hv[i].z * wv[j].z + hv[i].w * wv[j].w;
    }
    #pragma unroll 4
    for (int k4 = 0; k4 < 16; k4++) {
        float4 hv[4], wv[4];
        #pragma unroll
        for (int i = 0; i < 4; i++) hv[i] = *(const float4*)&hn[ng + i][k4 * 4];
        #pragma unroll
        for (int j = 0; j < 4; j++) wv[j] = Wa4[(og + j) * 32 + 16 + k4];
        #pragma unroll
        for (int i = 0; i < 4; i++)
            #pragma unroll
            for (int j = 0; j < 4; j++)
                acc2[i][j] += hv[i].x * wv[j].x + hv[i].y * wv[j].y +
                              hv[i].z * wv[j].z + hv[i].w * wv[j].w;
    }
    #pragma unroll
    for (int i = 0; i < 4; i++) {
        int n = base + ng + i;
        if (n < N_NODES) {
            float4 o;
            o.x = fmaxf(acc2[i][0] + ba[og + 0], 0.f);
            o.y = fmaxf(acc2[i][1] + ba[og + 1], 0.f);
            o.z = fmaxf(acc2[i][2] + ba[og + 2], 0.f);
            o.w = fmaxf(acc2[i][3] + ba[og + 3], 0.f);
            *(float4*)&out[(size_t)n * 64 + og] = o;
        }
    }
}

extern "C" void kernel_launch(void* const* d_in, const int* in_sizes, int n_in,
                              void* d_out, int out_size, void* d_ws, size_t ws_size,
                              hipStream_t stream) {
    const float* nf = (const float*)d_in[0];
    const float* ef = (const float*)d_in[1];
    const int* src = (const int*)d_in[2];
    const int* dst = (const int*)d_in[3];
    const float* Wm = (const float*)d_in[4];
    const float* bm = (const float*)d_in[5];
    const float* Wa = (const float*)d_in[6];
    const float* ba = (const float*)d_in[7];
    float* out = (float*)d_out;

    // ws layout (ints): cnt[N], off[N], cur[N], part[64], code32[E]  (~7.6 MB)
    int* cnt = (int*)d_ws;
    int* off = cnt + N_NODES;
    int* cur = off + N_NODES;
    int* part = cur + N_NODES;
    unsigned* code32 = (unsigned*)(part + 64);

    int nz = 3 * N_NODES + 64;  // zero cnt, off, cur, part (contiguous)
    k_zero<<<(nz + 255) / 256, 256, 0, stream>>>(cnt, nz);
    k_count<<<(N_EDGES + 255) / 256, 256, 0, stream>>>(dst, cnt);
    k_partial<<<NB_SCAN, 256, 0, stream>>>(cnt, part);
    k_scan_part<<<1, 64, 0, stream>>>(part, NB_SCAN);
    k_scan_chunks<<<NB_SCAN, 256, 0, stream>>>(cnt, part, off);
    k_scatter<<<(N_EDGES + 255) / 256, 256, 0, stream>>>(dst, off, cur, code32);
    k_node<<<(N_NODES + 63) / 64, 256, 0, stream>>>(nf, ef, src, cnt, off, code32,
                                                    Wm, bm, Wa, ba, out);
}

// Round 3
// 519.754 us; speedup vs baseline: 2.6781x; 2.6781x over previous
//
#include <hip/hip_runtime.h>

#define N_NODES 100000
#define N_EDGES 1600000
#define NB_SCAN 49  // ceil(100000/2048)

// ---------------- CSR build ----------------

__global__ void k_zero(int* __restrict__ p, int n) {
    int i = blockIdx.x * blockDim.x + threadIdx.x;
    if (i < n) p[i] = 0;
}

__global__ void k_count(const int* __restrict__ dst, int* __restrict__ cnt) {
    int e = blockIdx.x * blockDim.x + threadIdx.x;
    if (e < N_EDGES) atomicAdd(&cnt[dst[e]], 1);
}

__global__ void k_partial(const int* __restrict__ cnt, int* __restrict__ part) {
    __shared__ int red[256];
    int t = threadIdx.x;
    int base = blockIdx.x * 2048 + t * 8;
    int s = 0;
    if (base < N_NODES) {  // N_NODES % 8 == 0
        const int4* p = (const int4*)(cnt + base);
        int4 a = p[0], b = p[1];
        s = a.x + a.y + a.z + a.w + b.x + b.y + b.z + b.w;
    }
    red[t] = s;
    __syncthreads();
    for (int d = 128; d > 0; d >>= 1) {
        if (t < d) red[t] += red[t + d];
        __syncthreads();
    }
    if (t == 0) part[blockIdx.x] = red[0];
}

__global__ void k_scan_part(int* __restrict__ part, int nb) {
    int lane = threadIdx.x;
    int v = (lane < nb) ? part[lane] : 0;
    int incl = v;
    #pragma unroll
    for (int d = 1; d < 64; d <<= 1) {
        int u = __shfl_up(incl, d, 64);
        if (lane >= d) incl += u;
    }
    if (lane < nb) part[lane] = incl - v;
}

__global__ void k_scan_chunks(const int* __restrict__ cnt, const int* __restrict__ part,
                              int* __restrict__ off) {
    __shared__ int wtot[4];
    __shared__ int wexc[4];
    int t = threadIdx.x, b = blockIdx.x;
    int base = b * 2048 + t * 8;
    int4 a = {0, 0, 0, 0}, c = {0, 0, 0, 0};
    if (base < N_NODES) {
        const int4* p = (const int4*)(cnt + base);
        a = p[0];
        c = p[1];
    }
    int s0 = a.x, s1 = s0 + a.y, s2 = s1 + a.z, s3 = s2 + a.w;
    int s4 = s3 + c.x, s5 = s4 + c.y, s6 = s5 + c.z, s7 = s6 + c.w;
    int tot = s7;
    int lane = t & 63, wid = t >> 6;
    int incl = tot;
    #pragma unroll
    for (int d = 1; d < 64; d <<= 1) {
        int u = __shfl_up(incl, d, 64);
        if (lane >= d) incl += u;
    }
    if (lane == 63) wtot[wid] = incl;
    __syncthreads();
    if (t == 0) {
        int r = 0;
        for (int i = 0; i < 4; i++) { int v = wtot[i]; wexc[i] = r; r += v; }
    }
    __syncthreads();
    int texc = incl - tot + wexc[wid] + part[b];
    if (base < N_NODES) {
        int4 o0 = {texc, texc + s0, texc + s1, texc + s2};
        int4 o1 = {texc + s3, texc + s4, texc + s5, texc + s6};
        ((int4*)(off + base))[0] = o0;
        ((int4*)(off + base))[1] = o1;
    }
}

// split path: pack (src<<32)|e per CSR slot
__global__ void k_scatter64(const int* __restrict__ dst, const int* __restrict__ src,
                            const int* __restrict__ off, int* __restrict__ cur,
                            unsigned long long* __restrict__ code64) {
    int e = blockIdx.x * blockDim.x + threadIdx.x;
    if (e < N_EDGES) {
        int d = dst[e];
        int p = off[d] + atomicAdd(&cur[d], 1);
        code64[p] = ((unsigned long long)(unsigned)src[e] << 32) | (unsigned)e;
    }
}

// fallback path: edge id only
__global__ void k_scatter32(const int* __restrict__ dst, const int* __restrict__ off,
                            int* __restrict__ cur, int* __restrict__ eid) {
    int e = blockIdx.x * blockDim.x + threadIdx.x;
    if (e < N_EDGES) {
        int d = dst[e];
        int p = off[d] + atomicAdd(&cur[d], 1);
        eid[p] = e;
    }
}

// ---------------- split path: wave-per-node aggregation, no LDS ----------------
// 256 threads = 4 waves = 4 nodes. lane: half=lane>>5 (edge parity),
// slot=lane&31 owns dims [4s,4s+4): slot<16 -> nf slice, else ef slice.
// Register accumulation; 4x manual unroll -> 4 code loads + 4 feature loads
// in flight per lane; combine halves with one shfl_xor(32).
__device__ __forceinline__ float4 ld_feat(const float* __restrict__ nf,
                                          const float* __restrict__ ef,
                                          unsigned long long c, int slot) {
    unsigned e = (unsigned)c;
    unsigned sv = (unsigned)(c >> 32);
    const float* p = (slot < 16) ? (nf + (size_t)sv * 64 + slot * 4)
                                 : (ef + (size_t)e * 64 + (slot - 16) * 4);
    return *(const float4*)p;
}

__global__ __launch_bounds__(256) void k_agg(
    const float* __restrict__ nf, const float* __restrict__ ef,
    const int* __restrict__ cnt, const int* __restrict__ off,
    const unsigned long long* __restrict__ code64, float* __restrict__ aggG) {
    int tid = threadIdx.x, lane = tid & 63, wid = tid >> 6;
    int n = blockIdx.x * 4 + wid;
    if (n >= N_NODES) return;
    int slot = lane & 31, half = lane >> 5;
    int st = off[n], deg = cnt[n];
    int pend = st + deg;
    float4 acc = make_float4(0.f, 0.f, 0.f, 0.f);
    int p = st + half;  // this lane's edges: p, p+2, p+4, ...
    for (; p + 6 < pend; p += 8) {
        unsigned long long c0 = code64[p];
        unsigned long long c1 = code64[p + 2];
        unsigned long long c2 = code64[p + 4];
        unsigned long long c3 = code64[p + 6];
        float4 a0 = ld_feat(nf, ef, c0, slot);
        float4 a1 = ld_feat(nf, ef, c1, slot);
        float4 a2 = ld_feat(nf, ef, c2, slot);
        float4 a3 = ld_feat(nf, ef, c3, slot);
        acc.x += a0.x + a1.x + a2.x + a3.x;
        acc.y += a0.y + a1.y + a2.y + a3.y;
        acc.z += a0.z + a1.z + a2.z + a3.z;
        acc.w += a0.w + a1.w + a2.w + a3.w;
    }
    for (; p < pend; p += 2) {
        unsigned long long c = code64[p];
        float4 a = ld_feat(nf, ef, c, slot);
        acc.x += a.x; acc.y += a.y; acc.z += a.z; acc.w += a.w;
    }
    // combine the two halves
    acc.x += __shfl_xor(acc.x, 32, 64);
    acc.y += __shfl_xor(acc.y, 32, 64);
    acc.z += __shfl_xor(acc.z, 32, 64);
    acc.w += __shfl_xor(acc.w, 32, 64);
    if (half == 0) {
        *(float4*)(aggG + (size_t)n * 128 + slot * 4) = acc;
    }
}

// ---------------- split path: GEMM1 + GEMM2 + epilogue ----------------
__global__ __launch_bounds__(256) void k_gemm(
    const float* __restrict__ nf, const float* __restrict__ aggG,
    const int* __restrict__ cnt,
    const float* __restrict__ Wm, const float* __restrict__ bm,
    const float* __restrict__ Wa, const float* __restrict__ ba,
    float* __restrict__ out) {
    __shared__ __align__(16) float agg[64][132];
    __shared__ __align__(16) float hn[64][68];
    __shared__ float degl[64];

    int tid = threadIdx.x;
    int base = blockIdx.x * 64;

    // stage agg tile (64 x 128) coalesced
    {
        const float4* g4 = (const float4*)aggG;
        #pragma unroll
        for (int r = 0; r < 8; r++) {
            int f = r * 256 + tid;      // 0..2047
            int row = f >> 5, c4 = f & 31;
            float4 v = make_float4(0.f, 0.f, 0.f, 0.f);
            if (base + row < N_NODES) v = g4[(size_t)(base + row) * 32 + c4];
            *(float4*)&agg[row][c4 * 4] = v;
        }
        if (tid < 64) degl[tid] = (base + tid < N_NODES) ? (float)cnt[base + tid] : 0.f;
    }
    __syncthreads();

    // ---- GEMM1: hn = (Wm @ agg)/deg + bm ----
    int og = (tid & 15) * 4;   // output dim group
    int ng = (tid >> 4) * 4;   // node group
    float acc[4][4] = {};
    const float4* Wm4 = (const float4*)Wm;
    #pragma unroll 4
    for (int k4 = 0; k4 < 32; k4++) {
        float4 av[4], wv[4];
        #pragma unroll
        for (int i = 0; i < 4; i++) av[i] = *(const float4*)&agg[ng + i][k4 * 4];
        #pragma unroll
        for (int j = 0; j < 4; j++) wv[j] = Wm4[(og + j) * 32 + k4];
        #pragma unroll
        for (int i = 0; i < 4; i++)
            #pragma unroll
            for (int j = 0; j < 4; j++)
                acc[i][j] += av[i].x * wv[j].x + av[i].y * wv[j].y +
                             av[i].z * wv[j].z + av[i].w * wv[j].w;
    }
    #pragma unroll
    for (int i = 0; i < 4; i++) {
        float d = degl[ng + i];
        float inv = (d > 0.f) ? 1.f / d : 0.f;
        #pragma unroll
        for (int j = 0; j < 4; j++) {
            float v = (d > 0.f) ? acc[i][j] * inv + bm[og + j] : 0.f;
            hn[ng + i][og + j] = v;
        }
    }
    __syncthreads();

    // ---- GEMM2: out = relu(h @ WaH^T + hn @ WaN^T + ba) ----
    float acc2[4][4] = {};
    const float4* Wa4 = (const float4*)Wa;
    #pragma unroll 4
    for (int k4 = 0; k4 < 16; k4++) {
        float4 hv[4], wv[4];
        #pragma unroll
        for (int i = 0; i < 4; i++) {
            int n = base + ng + i;
            if (n < N_NODES)
                hv[i] = ((const float4*)(nf + (size_t)n * 64))[k4];
            else
                hv[i] = make_float4(0.f, 0.f, 0.f, 0.f);
        }
        #pragma unroll
        for (int j = 0; j < 4; j++) wv[j] = Wa4[(og + j) * 32 + k4];
        #pragma unroll
        for (int i = 0; i < 4; i++)
            #pragma unroll
            for (int j = 0; j < 4; j++)
                acc2[i][j] += hv[i].x * wv[j].x + hv[i].y * wv[j].y +
                              hv[i].z * wv[j].z + hv[i].w * wv[j].w;
    }
    #pragma unroll 4
    for (int k4 = 0; k4 < 16; k4++) {
        float4 hv[4], wv[4];
        #pragma unroll
        for (int i = 0; i < 4; i++) hv[i] = *(const float4*)&hn[ng + i][k4 * 4];
        #pragma unroll
        for (int j = 0; j < 4; j++) wv[j] = Wa4[(og + j) * 32 + 16 + k4];
        #pragma unroll
        for (int i = 0; i < 4; i++)
            #pragma unroll
            for (int j = 0; j < 4; j++)
                acc2[i][j] += hv[i].x * wv[j].x + hv[i].y * wv[j].y +
                              hv[i].z * wv[j].z + hv[i].w * wv[j].w;
    }
    #pragma unroll
    for (int i = 0; i < 4; i++) {
        int n = base + ng + i;
        if (n < N_NODES) {
            float4 o;
            o.x = fmaxf(acc2[i][0] + ba[og + 0], 0.f);
            o.y = fmaxf(acc2[i][1] + ba[og + 1], 0.f);
            o.z = fmaxf(acc2[i][2] + ba[og + 2], 0.f);
            o.w = fmaxf(acc2[i][3] + ba[og + 3], 0.f);
            *(float4*)&out[(size_t)n * 64 + og] = o;
        }
    }
}

// ---------------- fallback (round-1 kernel, known good) ----------------
__global__ __launch_bounds__(256) void k_node_fb(
    const float* __restrict__ nf, const float* __restrict__ ef,
    const int* __restrict__ src, const int* __restrict__ cnt,
    const int* __restrict__ off, const int* __restrict__ eid,
    const float* __restrict__ Wm, const float* __restrict__ bm,
    const float* __restrict__ Wa, const float* __restrict__ ba,
    float* __restrict__ out) {
    __shared__ __align__(16) float agg[64][132];
    __shared__ __align__(16) float hn[64][68];
    __shared__ float degl[64];

    int tid = threadIdx.x, lane = tid & 63, wid = tid >> 6;
    int base = blockIdx.x * 64;

    for (int q = 0; q < 16; q++) {
        int nl = wid * 16 + q;
        int n = base + nl;
        float sh = 0.f, se = 0.f;
        int dg = 0;
        if (n < N_NODES) {
            dg = cnt[n];
            int st = off[n];
            for (int c0 = 0; c0 < dg; c0 += 64) {
                int m = dg - c0;
                if (m > 64) m = 64;
                int e_l = 0, s_l = 0;
                if (lane < m) {
                    e_l = eid[st + c0 + lane];
                    s_l = src[e_l];
                }
                for (int j = 0; j < m; j++) {
                    int e = __shfl(e_l, j, 64);
                    int s = __shfl(s_l, j, 64);
                    sh += nf[(size_t)s * 64 + lane];
                    se += ef[(size_t)e * 64 + lane];
                }
            }
        }
        agg[nl][lane] = sh;
        agg[nl][64 + lane] = se;
        if (lane == 0) degl[nl] = (float)dg;
    }
    __syncthreads();

    int og = (tid & 15) * 4;
    int ng = (tid >> 4) * 4;
    float acc[4][4] = {};
    const float4* Wm4 = (const float4*)Wm;
    #pragma unroll 4
    for (int k4 = 0; k4 < 32; k4++) {
        float4 av[4], wv[4];
        #pragma unroll
        for (int i = 0; i < 4; i++) av[i] = *(const float4*)&agg[ng + i][k4 * 4];
        #pragma unroll
        for (int j = 0; j < 4; j++) wv[j] = Wm4[(og + j) * 32 + k4];
        #pragma unroll
        for (int i = 0; i < 4; i++)
            #pragma unroll
            for (int j = 0; j < 4; j++)
                acc[i][j] += av[i].x * wv[j].x + av[i].y * wv[j].y +
                             av[i].z * wv[j].z + av[i].w * wv[j].w;
    }
    #pragma unroll
    for (int i = 0; i < 4; i++) {
        float d = degl[ng + i];
        float inv = (d > 0.f) ? 1.f / d : 0.f;
        #pragma unroll
        for (int j = 0; j < 4; j++) {
            float v = (d > 0.f) ? acc[i][j] * inv + bm[og + j] : 0.f;
            hn[ng + i][og + j] = v;
        }
    }
    __syncthreads();

    float acc2[4][4] = {};
    const float4* Wa4 = (const float4*)Wa;
    #pragma unroll 4
    for (int k4 = 0; k4 < 16; k4++) {
        float4 hv[4], wv[4];
        #pragma unroll
        for (int i = 0; i < 4; i++) {
            int n = base + ng + i;
            if (n < N_NODES)
                hv[i] = ((const float4*)(nf + (size_t)n * 64))[k4];
            else
                hv[i] = make_float4(0.f, 0.f, 0.f, 0.f);
        }
        #pragma unroll
        for (int j = 0; j < 4; j++) wv[j] = Wa4[(og + j) * 32 + k4];
        #pragma unroll
        for (int i = 0; i < 4; i++)
            #pragma unroll
            for (int j = 0; j < 4; j++)
                acc2[i][j] += hv[i].x * wv[j].x + hv[i].y * wv[j].y +
                              hv[i].z * wv[j].z + hv[i].w * wv[j].w;
    }
    #pragma unroll 4
    for (int k4 = 0; k4 < 16; k4++) {
        float4 hv[4], wv[4];
        #pragma unroll
        for (int i = 0; i < 4; i++) hv[i] = *(const float4*)&hn[ng + i][k4 * 4];
        #pragma unroll
        for (int j = 0; j < 4; j++) wv[j] = Wa4[(og + j) * 32 + 16 + k4];
        #pragma unroll
        for (int i = 0; i < 4; i++)
            #pragma unroll
            for (int j = 0; j < 4; j++)
                acc2[i][j] += hv[i].x * wv[j].x + hv[i].y * wv[j].y +
                              hv[i].z * wv[j].z + hv[i].w * wv[j].w;
    }
    #pragma unroll
    for (int i = 0; i < 4; i++) {
        int n = base + ng + i;
        if (n < N_NODES) {
            float4 o;
            o.x = fmaxf(acc2[i][0] + ba[og + 0], 0.f);
            o.y = fmaxf(acc2[i][1] + ba[og + 1], 0.f);
            o.z = fmaxf(acc2[i][2] + ba[og + 2], 0.f);
            o.w = fmaxf(acc2[i][3] + ba[og + 3], 0.f);
            *(float4*)&out[(size_t)n * 64 + og] = o;
        }
    }
}

extern "C" void kernel_launch(void* const* d_in, const int* in_sizes, int n_in,
                              void* d_out, int out_size, void* d_ws, size_t ws_size,
                              hipStream_t stream) {
    const float* nf = (const float*)d_in[0];
    const float* ef = (const float*)d_in[1];
    const int* src = (const int*)d_in[2];
    const int* dst = (const int*)d_in[3];
    const float* Wm = (const float*)d_in[4];
    const float* bm = (const float*)d_in[5];
    const float* Wa = (const float*)d_in[6];
    const float* ba = (const float*)d_in[7];
    float* out = (float*)d_out;

    // common CSR scratch: cnt[N], off[N], cur[N], part[64]
    int* cnt = (int*)d_ws;
    int* off = cnt + N_NODES;
    int* cur = off + N_NODES;
    int* part = cur + N_NODES;
    size_t csr_bytes = (size_t)(3 * N_NODES + 64) * 4;  // 1,200,256 (8B-aligned)

    int nz = 3 * N_NODES + 64;
    k_zero<<<(nz + 255) / 256, 256, 0, stream>>>(cnt, nz);
    k_count<<<(N_EDGES + 255) / 256, 256, 0, stream>>>(dst, cnt);
    k_partial<<<NB_SCAN, 256, 0, stream>>>(cnt, part);
    k_scan_part<<<1, 64, 0, stream>>>(part, NB_SCAN);
    k_scan_chunks<<<NB_SCAN, 256, 0, stream>>>(cnt, part, off);

    size_t split_need = csr_bytes + (size_t)N_EDGES * 8 + (size_t)N_NODES * 128 * 4;
    if (ws_size >= split_need) {
        unsigned long long* code64 = (unsigned long long*)((char*)d_ws + csr_bytes);
        float* aggG = (float*)((char*)d_ws + csr_bytes + (size_t)N_EDGES * 8);
        k_scatter64<<<(N_EDGES + 255) / 256, 256, 0, stream>>>(dst, src, off, cur, code64);
        k_agg<<<N_NODES / 4, 256, 0, stream>>>(nf, ef, cnt, off, code64, aggG);
        k_gemm<<<(N_NODES + 63) / 64, 256, 0, stream>>>(nf, aggG, cnt, Wm, bm, Wa, ba, out);
    } else {
        int* eid = part + 64;
        k_scatter32<<<(N_EDGES + 255) / 256, 256, 0, stream>>>(dst, off, cur, eid);
        k_node_fb<<<(N_NODES + 63) / 64, 256, 0, stream>>>(nf, ef, src, cnt, off, eid,
                                                           Wm, bm, Wa, ba, out);
    }
}